// Round 3
// baseline (148.267 us; speedup 1.0000x reference)
//
#include <hip/hip_runtime.h>
#include <stdint.h>

// ScoreNet: S[b] = (x_b Wq^T)(x_b Wk^T)^T * (1/sqrt(R)) + diag(x_b Wd^T + bd), * max(ls, 0.01)
// B=16, L=2048 -> N=1024, C=256, H*R=192.
//
// R3 design: both GEMMs are LDS-free / barrier-free. Q,K (768 KB/batch) and
// W (192 KB) are L2-resident, so each wave loads its MFMA fragments directly
// from global (b128 per lane) and the compiler software-pipelines loads
// against MFMAs with no syncthreads drains.

#define HD_SCALE 0.17677669529663687f  // 1/sqrt(32)

typedef __bf16 bf16_t;
typedef bf16_t bf16x8 __attribute__((ext_vector_type(8)));
typedef float f32x4 __attribute__((ext_vector_type(4)));

__device__ __forceinline__ unsigned short f2bf(float f) {
  // round-to-nearest-even fp32 -> bf16 bits
  unsigned int u = __float_as_uint(f);
  return (unsigned short)((u + 0x7fffu + ((u >> 16) & 1u)) >> 16);
}

// ---------------------------------------------------------------------------
// Kernel 1: fold pairs of rows (mean) -> xb (bf16), d = x.Wd + bd (fp32),
// and (first 384 blocks) pack [Wq;Wk] fp32 -> bf16.
// ---------------------------------------------------------------------------
__global__ __launch_bounds__(256) void k_prep(const float* __restrict__ feats,
                                              const float* __restrict__ Wq,
                                              const float* __restrict__ Wk,
                                              const float* __restrict__ Wd,
                                              const float* __restrict__ bd,
                                              unsigned short* __restrict__ xb,
                                              float* __restrict__ dvec,
                                              unsigned short* __restrict__ Wqkb) {
  const int t = threadIdx.x;
  if (blockIdx.x < 384) {  // weight conversion: 384*256 = 98304 elements
    const int idx = blockIdx.x * 256 + t;
    const float v = (idx < 49152) ? Wq[idx] : Wk[idx - 49152];
    Wqkb[idx] = f2bf(v);
  }
  const int wave = t >> 6, lane = t & 63;
  const int gr = blockIdx.x * 4 + wave;  // global row = b*1024 + n
  const int b = gr >> 10, n = gr & 1023;
  const int c = lane * 4;

  const float* r0 = feats + (size_t)(b * 2049 + 1 + 2 * n) * 256 + c;
  float4 p0 = *(const float4*)r0;
  float4 p1 = *(const float4*)(r0 + 256);
  float4 wv = *(const float4*)(Wd + c);

  float x0 = (p0.x + p1.x) * 0.5f;
  float x1 = (p0.y + p1.y) * 0.5f;
  float x2 = (p0.z + p1.z) * 0.5f;
  float x3 = (p0.w + p1.w) * 0.5f;

  ushort4 xs;
  xs.x = f2bf(x0); xs.y = f2bf(x1); xs.z = f2bf(x2); xs.w = f2bf(x3);
  *(ushort4*)&xb[(size_t)gr * 256 + c] = xs;

  float dot = x0 * wv.x + x1 * wv.y + x2 * wv.z + x3 * wv.w;
#pragma unroll
  for (int o = 32; o > 0; o >>= 1) dot += __shfl_down(dot, o, 64);
  if (lane == 0) dvec[gr] = dot + bd[0];
}

// ---------------------------------------------------------------------------
// Kernel 2: projection GEMM  QK[16384][384] = xb[16384][256] @ Wqkb[384][256]^T
// LDS-free: 128x64 tile, grid (128,6)=768 blocks. 4 waves 2x2; wave = 64x32.
// Fragments loaded straight from global (xb rows fresh from HBM, W L2-hot).
// ---------------------------------------------------------------------------
__global__ __launch_bounds__(256) void k_proj(const unsigned short* __restrict__ xb,
                                              const unsigned short* __restrict__ Wqkb,
                                              unsigned short* __restrict__ QK) {
  const int t = threadIdx.x;
  const int w = t >> 6, l = t & 63;
  const int m0 = blockIdx.x * 128;  // rows in 16384
  const int n0 = blockIdx.y * 64;   // cols in 384
  const int wm = w >> 1, wn = w & 1;
  const int quad = l >> 4, lr = l & 15;

  const unsigned short* ap = xb + (size_t)(m0 + wm * 64 + lr) * 256 + quad * 8;
  const unsigned short* bp = Wqkb + (size_t)(n0 + wn * 32 + lr) * 256 + quad * 8;

  f32x4 acc[4][2] = {};
#pragma unroll
  for (int kk = 0; kk < 8; ++kk) {
    bf16x8 a[4], bb[2];
#pragma unroll
    for (int i = 0; i < 4; ++i)
      a[i] = *(const bf16x8*)(ap + (size_t)(i * 16) * 256 + kk * 32);
#pragma unroll
    for (int j = 0; j < 2; ++j)
      bb[j] = *(const bf16x8*)(bp + (size_t)(j * 16) * 256 + kk * 32);
#pragma unroll
    for (int i = 0; i < 4; ++i)
#pragma unroll
      for (int j = 0; j < 2; ++j)
        acc[i][j] = __builtin_amdgcn_mfma_f32_16x16x32_bf16(a[i], bb[j],
                                                            acc[i][j], 0, 0, 0);
  }

#pragma unroll
  for (int i = 0; i < 4; ++i)
#pragma unroll
    for (int j = 0; j < 2; ++j)
#pragma unroll
      for (int r = 0; r < 4; ++r) {
        const int row = m0 + wm * 64 + i * 16 + quad * 4 + r;
        const int col = n0 + wn * 32 + j * 16 + lr;
        QK[(size_t)row * 384 + col] = f2bf(acc[i][j][r]);
      }
}

// ---------------------------------------------------------------------------
// Kernel 3: S[b] = Q[b] @ K[b]^T * HD_SCALE (+ diag d) * ls
// LDS-free 128x128 tile; Q = QK[b*1024+n][0:192], K = QK[b*1024+m][192:384].
// 48 b128 global loads (L2-hot) against 96 MFMAs per wave, no barriers.
// ---------------------------------------------------------------------------
__global__ __launch_bounds__(256) void k_score(const unsigned short* __restrict__ QK,
                                               const float* __restrict__ dvec,
                                               const float* __restrict__ logit_scale,
                                               float* __restrict__ out) {
  const int t = threadIdx.x;
  const int w = t >> 6, l = t & 63;
  const int mt = blockIdx.x, nt = blockIdx.y, b = blockIdx.z;
  const int m0 = mt * 128;  // cols of S (K rows)
  const int n0 = nt * 128;  // rows of S (Q rows)
  const int wm = w >> 1, wn = w & 1;
  const int quad = l >> 4, lr = l & 15;
  const size_t qbase = (size_t)b * 1024 * 384;

  const unsigned short* qp = QK + qbase + (size_t)(n0 + wm * 64 + lr) * 384 + quad * 8;
  const unsigned short* kp = QK + qbase + (size_t)(m0 + wn * 64 + lr) * 384 + 192 + quad * 8;

  f32x4 acc[4][4] = {};
#pragma unroll
  for (int kk = 0; kk < 6; ++kk) {
    bf16x8 a[4], bb[4];
#pragma unroll
    for (int i = 0; i < 4; ++i)
      a[i] = *(const bf16x8*)(qp + (size_t)(i * 16) * 384 + kk * 32);
#pragma unroll
    for (int j = 0; j < 4; ++j)
      bb[j] = *(const bf16x8*)(kp + (size_t)(j * 16) * 384 + kk * 32);
#pragma unroll
    for (int i = 0; i < 4; ++i)
#pragma unroll
      for (int j = 0; j < 4; ++j)
        acc[i][j] = __builtin_amdgcn_mfma_f32_16x16x32_bf16(a[i], bb[j],
                                                            acc[i][j], 0, 0, 0);
  }

  const float ls = fmaxf(logit_scale[0], 0.01f);
  const bool diag_block = (m0 == n0);
#pragma unroll
  for (int i = 0; i < 4; ++i)
#pragma unroll
    for (int j = 0; j < 4; ++j)
#pragma unroll
      for (int r = 0; r < 4; ++r) {
        const int nr = n0 + wm * 64 + i * 16 + quad * 4 + r;  // S row
        const int mc = m0 + wn * 64 + j * 16 + lr;            // S col
        float v = acc[i][j][r] * HD_SCALE;
        if (diag_block && nr == mc) v += dvec[b * 1024 + nr];
        __builtin_nontemporal_store(v * ls,
            &out[((size_t)b << 20) + (size_t)nr * 1024 + mc]);
      }
}

// ---------------------------------------------------------------------------
extern "C" void kernel_launch(void* const* d_in, const int* in_sizes, int n_in,
                              void* d_out, int out_size, void* d_ws, size_t ws_size,
                              hipStream_t stream) {
  const float* feats = (const float*)d_in[0];  // (16, 2049, 256)
  const float* Wq = (const float*)d_in[1];     // (192, 256)
  const float* Wk = (const float*)d_in[2];     // (192, 256)
  const float* Wd = (const float*)d_in[3];     // (1, 256)
  const float* bd = (const float*)d_in[4];     // (1,)
  const float* ls = (const float*)d_in[5];     // scalar
  float* out = (float*)d_out;                  // (16, 1024, 1024) fp32

  uint8_t* ws = (uint8_t*)d_ws;
  unsigned short* xb = (unsigned short*)ws;                          // 8 MB bf16 x
  unsigned short* QK = (unsigned short*)(ws + (8u << 20));           // 12 MB bf16 [Q|K]
  float* dvec = (float*)(ws + (20u << 20));                          // 64 KB fp32 d
  unsigned short* Wqkb = (unsigned short*)(ws + (20u << 20) + (64u << 10));  // 192 KB

  hipLaunchKernelGGL(k_prep, dim3(4096), dim3(256), 0, stream, feats, Wq, Wk, Wd, bd,
                     xb, dvec, Wqkb);
  hipLaunchKernelGGL(k_proj, dim3(128, 6), dim3(256), 0, stream, xb, Wqkb, QK);
  hipLaunchKernelGGL(k_score, dim3(8, 8, 16), dim3(256), 0, stream, QK, dvec, ls, out);
}

// Round 4
// 133.285 us; speedup vs baseline: 1.1124x; 1.1124x over previous
//
#include <hip/hip_runtime.h>
#include <stdint.h>

// ScoreNet: S[b] = (x_b Wq^T)(x_b Wk^T)^T * (1/sqrt(R)) + diag(x_b Wd^T + bd), * max(ls, 0.01)
// B=16, L=2048 -> N=1024, C=256, H*R=192.
//
// R4: k_prep/k_proj = R2 (best known). k_score restructured: single-barrier
// hybrid — K-tile (full depth 192) staged in LDS (padded rows, 2-way-free
// banks), Q fragments direct from L2. No per-iteration barrier drains.

#define HD_SCALE 0.17677669529663687f  // 1/sqrt(32)

typedef __bf16 bf16_t;
typedef bf16_t bf16x8 __attribute__((ext_vector_type(8)));
typedef float f32x4 __attribute__((ext_vector_type(4)));

__device__ __forceinline__ unsigned short f2bf(float f) {
  unsigned int u = __float_as_uint(f);
  return (unsigned short)((u + 0x7fffu + ((u >> 16) & 1u)) >> 16);
}

__device__ __forceinline__ void gload16(const void* g, void* l) {
  __builtin_amdgcn_global_load_lds(
      (const __attribute__((address_space(1))) void*)g,
      (__attribute__((address_space(3))) void*)l, 16, 0, 0);
}

// ---------------------------------------------------------------------------
// Kernel 1: fold pairs of rows (mean) -> xb (bf16), d = x.Wd + bd (fp32),
// and (first 384 blocks) pack [Wq;Wk] fp32 -> bf16.
// ---------------------------------------------------------------------------
__global__ __launch_bounds__(256) void k_prep(const float* __restrict__ feats,
                                              const float* __restrict__ Wq,
                                              const float* __restrict__ Wk,
                                              const float* __restrict__ Wd,
                                              const float* __restrict__ bd,
                                              unsigned short* __restrict__ xb,
                                              float* __restrict__ dvec,
                                              unsigned short* __restrict__ Wqkb) {
  const int t = threadIdx.x;
  if (blockIdx.x < 384) {
    const int idx = blockIdx.x * 256 + t;
    const float v = (idx < 49152) ? Wq[idx] : Wk[idx - 49152];
    Wqkb[idx] = f2bf(v);
  }
  const int wave = t >> 6, lane = t & 63;
  const int gr = blockIdx.x * 4 + wave;
  const int b = gr >> 10, n = gr & 1023;
  const int c = lane * 4;

  const float* r0 = feats + (size_t)(b * 2049 + 1 + 2 * n) * 256 + c;
  float4 p0 = *(const float4*)r0;
  float4 p1 = *(const float4*)(r0 + 256);
  float4 wv = *(const float4*)(Wd + c);

  float x0 = (p0.x + p1.x) * 0.5f;
  float x1 = (p0.y + p1.y) * 0.5f;
  float x2 = (p0.z + p1.z) * 0.5f;
  float x3 = (p0.w + p1.w) * 0.5f;

  ushort4 xs;
  xs.x = f2bf(x0); xs.y = f2bf(x1); xs.z = f2bf(x2); xs.w = f2bf(x3);
  *(ushort4*)&xb[(size_t)gr * 256 + c] = xs;

  float dot = x0 * wv.x + x1 * wv.y + x2 * wv.z + x3 * wv.w;
#pragma unroll
  for (int o = 32; o > 0; o >>= 1) dot += __shfl_down(dot, o, 64);
  if (lane == 0) dvec[gr] = dot + bd[0];
}

// ---------------------------------------------------------------------------
// Kernel 2 (R2 form): QK[16384][384] = xb[16384][256] @ Wqkb[384][256]^T
// 128x128 tile, BK=64, XOR-swizzled LDS.
// ---------------------------------------------------------------------------
__global__ __launch_bounds__(256) void k_proj(const unsigned short* __restrict__ xb,
                                              const unsigned short* __restrict__ Wqkb,
                                              unsigned short* __restrict__ QK) {
  __shared__ unsigned short As[128 * 64];
  __shared__ unsigned short Bs[128 * 64];
  const int t = threadIdx.x;
  const int w = t >> 6, l = t & 63;
  const int m0 = blockIdx.x * 128;
  const int n0 = blockIdx.y * 128;
  const int wm = w >> 1, wn = w & 1;
  const int quad = l >> 4, lr = l & 15;

  f32x4 acc[4][4] = {};

  for (int kk = 0; kk < 4; ++kk) {
    const int k0 = kk * 64;
    __syncthreads();
#pragma unroll
    for (int i = 0; i < 4; ++i) {
      const int e = i * 256 + t;
      const int row = e >> 3;
      const int kc = (e & 7) ^ (row & 7);
      gload16(xb + (size_t)(m0 + row) * 256 + k0 + kc * 8,
              &As[(i * 256 + (w << 6)) * 8]);
      gload16(Wqkb + (size_t)(n0 + row) * 256 + k0 + kc * 8,
              &Bs[(i * 256 + (w << 6)) * 8]);
    }
    __syncthreads();

#pragma unroll
    for (int s = 0; s < 2; ++s) {
      bf16x8 a[4], bb[4];
#pragma unroll
      for (int i = 0; i < 4; ++i) {
        const int row = wm * 64 + i * 16 + lr;
        const int pos = (s * 4 + quad) ^ (row & 7);
        a[i] = *(const bf16x8*)&As[row * 64 + pos * 8];
      }
#pragma unroll
      for (int j = 0; j < 4; ++j) {
        const int row = wn * 64 + j * 16 + lr;
        const int pos = (s * 4 + quad) ^ (row & 7);
        bb[j] = *(const bf16x8*)&Bs[row * 64 + pos * 8];
      }
#pragma unroll
      for (int i = 0; i < 4; ++i)
#pragma unroll
        for (int j = 0; j < 4; ++j)
          acc[i][j] = __builtin_amdgcn_mfma_f32_16x16x32_bf16(a[i], bb[j],
                                                              acc[i][j], 0, 0, 0);
    }
  }

#pragma unroll
  for (int i = 0; i < 4; ++i)
#pragma unroll
    for (int j = 0; j < 4; ++j)
#pragma unroll
      for (int r = 0; r < 4; ++r) {
        const int row = m0 + wm * 64 + i * 16 + quad * 4 + r;
        const int col = n0 + wn * 64 + j * 16 + lr;
        QK[(size_t)row * 384 + col] = f2bf(acc[i][j][r]);
      }
}

// ---------------------------------------------------------------------------
// Kernel 3: S[b] = Q[b] @ K[b]^T * HD_SCALE (+ diag d) * ls
// Single-barrier hybrid: full-depth K-tile (128x192) staged in LDS with
// padded rows (25 x 16B chunks = 400 B stride -> 2-way bank aliasing, free).
// Q fragments read direct from global (L2/L1-hot). No per-iter barriers.
// ---------------------------------------------------------------------------
__global__ __launch_bounds__(256) void k_score(const unsigned short* __restrict__ QK,
                                               const float* __restrict__ dvec,
                                               const float* __restrict__ logit_scale,
                                               float* __restrict__ out) {
  __shared__ unsigned short Bs[128 * 25 * 8];  // 128 rows x 25 chunks x 16B = 50 KB
  const int t = threadIdx.x;
  const int w = t >> 6, l = t & 63;
  const int mt = blockIdx.x, nt = blockIdx.y, b = blockIdx.z;
  const int m0 = mt * 128;  // cols of S (K rows)
  const int n0 = nt * 128;  // rows of S (Q rows)
  const int wm = w >> 1, wn = w & 1;
  const int quad = l >> 4, lr = l & 15;
  const size_t qbase = (size_t)b * 1024 * 384;

  // ---- stage K-tile: 128 rows x 24 real chunks into 25-chunk padded rows ----
  // chunk index space: 0..3199 (row*25 + pos); pos 24 = pad (dup of 23).
#pragma unroll
  for (int i = 0; i < 13; ++i) {
    const int chunk = i * 256 + t;
    if (chunk < 3200) {
      const int row = (int)(((unsigned long long)chunk * 1374389535ull) >> 35);  // /25
      int pos = chunk - row * 25;
      if (pos > 23) pos = 23;
      gload16(QK + qbase + (size_t)(m0 + row) * 384 + 192 + pos * 8,
              &Bs[(size_t)(i * 256 + (w << 6)) * 8]);
    }
  }

  const unsigned short* qp =
      QK + qbase + (size_t)(n0 + wm * 64 + lr) * 384 + quad * 8;

  __syncthreads();  // the only barrier: waits staging (vmcnt) + all waves

  f32x4 acc[4][4] = {};
#pragma unroll
  for (int kk = 0; kk < 6; ++kk) {
    bf16x8 a[4], bb[4];
#pragma unroll
    for (int i = 0; i < 4; ++i)
      a[i] = *(const bf16x8*)(qp + (size_t)(i * 16) * 384 + kk * 32);
#pragma unroll
    for (int j = 0; j < 4; ++j) {
      const int row = wn * 64 + j * 16 + lr;
      bb[j] = *(const bf16x8*)&Bs[(row * 25 + kk * 4 + quad) * 8];
    }
#pragma unroll
    for (int i = 0; i < 4; ++i)
#pragma unroll
      for (int j = 0; j < 4; ++j)
        acc[i][j] = __builtin_amdgcn_mfma_f32_16x16x32_bf16(a[i], bb[j],
                                                            acc[i][j], 0, 0, 0);
  }

  const float ls = fmaxf(logit_scale[0], 0.01f);
  const bool diag_block = (m0 == n0);
#pragma unroll
  for (int i = 0; i < 4; ++i)
#pragma unroll
    for (int j = 0; j < 4; ++j)
#pragma unroll
      for (int r = 0; r < 4; ++r) {
        const int nr = n0 + wm * 64 + i * 16 + quad * 4 + r;  // S row
        const int mc = m0 + wn * 64 + j * 16 + lr;            // S col
        float v = acc[i][j][r] * HD_SCALE;
        if (diag_block && nr == mc) v += dvec[b * 1024 + nr];
        __builtin_nontemporal_store(v * ls,
            &out[((size_t)b << 20) + (size_t)nr * 1024 + mc]);
      }
}

// ---------------------------------------------------------------------------
extern "C" void kernel_launch(void* const* d_in, const int* in_sizes, int n_in,
                              void* d_out, int out_size, void* d_ws, size_t ws_size,
                              hipStream_t stream) {
  const float* feats = (const float*)d_in[0];  // (16, 2049, 256)
  const float* Wq = (const float*)d_in[1];     // (192, 256)
  const float* Wk = (const float*)d_in[2];     // (192, 256)
  const float* Wd = (const float*)d_in[3];     // (1, 256)
  const float* bd = (const float*)d_in[4];     // (1,)
  const float* ls = (const float*)d_in[5];     // scalar
  float* out = (float*)d_out;                  // (16, 1024, 1024) fp32

  uint8_t* ws = (uint8_t*)d_ws;
  unsigned short* xb = (unsigned short*)ws;                          // 8 MB bf16 x
  unsigned short* QK = (unsigned short*)(ws + (8u << 20));           // 12 MB bf16 [Q|K]
  float* dvec = (float*)(ws + (20u << 20));                          // 64 KB fp32 d
  unsigned short* Wqkb = (unsigned short*)(ws + (20u << 20) + (64u << 10));  // 192 KB

  hipLaunchKernelGGL(k_prep, dim3(4096), dim3(256), 0, stream, feats, Wq, Wk, Wd, bd,
                     xb, dvec, Wqkb);
  hipLaunchKernelGGL(k_proj, dim3(128, 3), dim3(256), 0, stream, xb, Wqkb, QK);
  hipLaunchKernelGGL(k_score, dim3(8, 8, 16), dim3(256), 0, stream, QK, dvec, ls, out);
}

// Round 5
// 132.307 us; speedup vs baseline: 1.1206x; 1.0074x over previous
//
#include <hip/hip_runtime.h>
#include <stdint.h>

// ScoreNet: S[b] = (x_b Wq^T)(x_b Wk^T)^T * (1/sqrt(R)) + diag(x_b Wd^T + bd), * max(ls, 0.01)
// B=16, L=2048 -> N=1024, C=256, H*R=192.
//
// R5: k_prep unchanged. k_proj -> 128x64 tiles (768 blocks, 3/CU balanced).
// k_score -> 128x256 tile (wave 64x128, acc[4][8]): 25% less L2 staging
// fetch, 25% less LDS traffic, ds_read:MFMA = 0.375.

#define HD_SCALE 0.17677669529663687f  // 1/sqrt(32)

typedef __bf16 bf16_t;
typedef bf16_t bf16x8 __attribute__((ext_vector_type(8)));
typedef float f32x4 __attribute__((ext_vector_type(4)));

__device__ __forceinline__ unsigned short f2bf(float f) {
  unsigned int u = __float_as_uint(f);
  return (unsigned short)((u + 0x7fffu + ((u >> 16) & 1u)) >> 16);
}

__device__ __forceinline__ void gload16(const void* g, void* l) {
  __builtin_amdgcn_global_load_lds(
      (const __attribute__((address_space(1))) void*)g,
      (__attribute__((address_space(3))) void*)l, 16, 0, 0);
}

// ---------------------------------------------------------------------------
// Kernel 1: fold pairs of rows (mean) -> xb (bf16), d = x.Wd + bd (fp32),
// and (first 384 blocks) pack [Wq;Wk] fp32 -> bf16.
// ---------------------------------------------------------------------------
__global__ __launch_bounds__(256) void k_prep(const float* __restrict__ feats,
                                              const float* __restrict__ Wq,
                                              const float* __restrict__ Wk,
                                              const float* __restrict__ Wd,
                                              const float* __restrict__ bd,
                                              unsigned short* __restrict__ xb,
                                              float* __restrict__ dvec,
                                              unsigned short* __restrict__ Wqkb) {
  const int t = threadIdx.x;
  if (blockIdx.x < 384) {
    const int idx = blockIdx.x * 256 + t;
    const float v = (idx < 49152) ? Wq[idx] : Wk[idx - 49152];
    Wqkb[idx] = f2bf(v);
  }
  const int wave = t >> 6, lane = t & 63;
  const int gr = blockIdx.x * 4 + wave;
  const int b = gr >> 10, n = gr & 1023;
  const int c = lane * 4;

  const float* r0 = feats + (size_t)(b * 2049 + 1 + 2 * n) * 256 + c;
  float4 p0 = *(const float4*)r0;
  float4 p1 = *(const float4*)(r0 + 256);
  float4 wv = *(const float4*)(Wd + c);

  float x0 = (p0.x + p1.x) * 0.5f;
  float x1 = (p0.y + p1.y) * 0.5f;
  float x2 = (p0.z + p1.z) * 0.5f;
  float x3 = (p0.w + p1.w) * 0.5f;

  ushort4 xs;
  xs.x = f2bf(x0); xs.y = f2bf(x1); xs.z = f2bf(x2); xs.w = f2bf(x3);
  *(ushort4*)&xb[(size_t)gr * 256 + c] = xs;

  float dot = x0 * wv.x + x1 * wv.y + x2 * wv.z + x3 * wv.w;
#pragma unroll
  for (int o = 32; o > 0; o >>= 1) dot += __shfl_down(dot, o, 64);
  if (lane == 0) dvec[gr] = dot + bd[0];
}

// ---------------------------------------------------------------------------
// Kernel 2: QK[16384][384] = xb[16384][256] @ Wqkb[384][256]^T
// 128x64 tile, BK=64, XOR-swizzled LDS, grid (128,6)=768 blocks (3/CU).
// Waves 2x2, wave tile 64x32, acc[4][2].
// ---------------------------------------------------------------------------
__global__ __launch_bounds__(256) void k_proj(const unsigned short* __restrict__ xb,
                                              const unsigned short* __restrict__ Wqkb,
                                              unsigned short* __restrict__ QK) {
  __shared__ unsigned short As[128 * 64];  // 16 KB
  __shared__ unsigned short Bs[64 * 64];   // 8 KB
  const int t = threadIdx.x;
  const int w = t >> 6, l = t & 63;
  const int m0 = blockIdx.x * 128;  // rows in 16384
  const int n0 = blockIdx.y * 64;   // cols in 384
  const int wm = w >> 1, wn = w & 1;
  const int quad = l >> 4, lr = l & 15;

  f32x4 acc[4][2] = {};

  for (int kk = 0; kk < 4; ++kk) {
    const int k0 = kk * 64;
    __syncthreads();
#pragma unroll
    for (int i = 0; i < 4; ++i) {  // A: 1024 chunks
      const int e = i * 256 + t;
      const int row = e >> 3;
      const int kc = (e & 7) ^ (row & 7);
      gload16(xb + (size_t)(m0 + row) * 256 + k0 + kc * 8,
              &As[(i * 256 + (w << 6)) * 8]);
    }
#pragma unroll
    for (int i = 0; i < 2; ++i) {  // B: 512 chunks
      const int e = i * 256 + t;
      const int row = e >> 3;
      const int kc = (e & 7) ^ (row & 7);
      gload16(Wqkb + (size_t)(n0 + row) * 256 + k0 + kc * 8,
              &Bs[(i * 256 + (w << 6)) * 8]);
    }
    __syncthreads();

#pragma unroll
    for (int s = 0; s < 2; ++s) {
      bf16x8 a[4], bb[2];
#pragma unroll
      for (int i = 0; i < 4; ++i) {
        const int row = wm * 64 + i * 16 + lr;
        const int pos = (s * 4 + quad) ^ (row & 7);
        a[i] = *(const bf16x8*)&As[row * 64 + pos * 8];
      }
#pragma unroll
      for (int j = 0; j < 2; ++j) {
        const int row = wn * 32 + j * 16 + lr;
        const int pos = (s * 4 + quad) ^ (row & 7);
        bb[j] = *(const bf16x8*)&Bs[row * 64 + pos * 8];
      }
#pragma unroll
      for (int i = 0; i < 4; ++i)
#pragma unroll
        for (int j = 0; j < 2; ++j)
          acc[i][j] = __builtin_amdgcn_mfma_f32_16x16x32_bf16(a[i], bb[j],
                                                              acc[i][j], 0, 0, 0);
    }
  }

#pragma unroll
  for (int i = 0; i < 4; ++i)
#pragma unroll
    for (int j = 0; j < 2; ++j)
#pragma unroll
      for (int r = 0; r < 4; ++r) {
        const int row = m0 + wm * 64 + i * 16 + quad * 4 + r;
        const int col = n0 + wn * 32 + j * 16 + lr;
        QK[(size_t)row * 384 + col] = f2bf(acc[i][j][r]);
      }
}

// ---------------------------------------------------------------------------
// Kernel 3: S[b] = Q[b] @ K[b]^T * HD_SCALE (+ diag d) * ls
// 128(n) x 256(m) tile, BK=64, swizzled LDS. Waves 2x2, wave tile 64x128,
// acc[4][8] (128 VGPRs). Grid (4,8,16)=512 blocks, 2/CU.
// ---------------------------------------------------------------------------
__global__ __launch_bounds__(256) void k_score(const unsigned short* __restrict__ QK,
                                               const float* __restrict__ dvec,
                                               const float* __restrict__ logit_scale,
                                               float* __restrict__ out) {
  __shared__ unsigned short As[128 * 64];  // Q tile: 16 KB
  __shared__ unsigned short Bs[256 * 64];  // K tile: 32 KB
  const int t = threadIdx.x;
  const int w = t >> 6, l = t & 63;
  const int mt = blockIdx.x, nt = blockIdx.y, b = blockIdx.z;
  const int m0 = mt * 256;  // cols of S (K rows)
  const int n0 = nt * 128;  // rows of S (Q rows)
  const int wm = w >> 1, wn = w & 1;
  const int quad = l >> 4, lr = l & 15;
  const size_t qbase = (size_t)b * 1024 * 384;

  f32x4 acc[4][8] = {};

  for (int kk = 0; kk < 3; ++kk) {
    const int k0 = kk * 64;
    __syncthreads();
#pragma unroll
    for (int i = 0; i < 4; ++i) {  // A (Q): 1024 chunks
      const int e = i * 256 + t;
      const int row = e >> 3;
      const int kc = (e & 7) ^ (row & 7);
      gload16(QK + qbase + (size_t)(n0 + row) * 384 + k0 + kc * 8,
              &As[(i * 256 + (w << 6)) * 8]);
    }
#pragma unroll
    for (int i = 0; i < 8; ++i) {  // B (K): 2048 chunks
      const int e = i * 256 + t;
      const int row = e >> 3;
      const int kc = (e & 7) ^ (row & 7);
      gload16(QK + qbase + (size_t)(m0 + row) * 384 + 192 + k0 + kc * 8,
              &Bs[(i * 256 + (w << 6)) * 8]);
    }
    __syncthreads();

#pragma unroll
    for (int s = 0; s < 2; ++s) {
      bf16x8 a[4], bb[8];
#pragma unroll
      for (int i = 0; i < 4; ++i) {
        const int row = wm * 64 + i * 16 + lr;
        const int pos = (s * 4 + quad) ^ (row & 7);
        a[i] = *(const bf16x8*)&As[row * 64 + pos * 8];
      }
#pragma unroll
      for (int j = 0; j < 8; ++j) {
        const int row = wn * 128 + j * 16 + lr;
        const int pos = (s * 4 + quad) ^ (row & 7);
        bb[j] = *(const bf16x8*)&Bs[row * 64 + pos * 8];
      }
#pragma unroll
      for (int i = 0; i < 4; ++i)
#pragma unroll
        for (int j = 0; j < 8; ++j)
          acc[i][j] = __builtin_amdgcn_mfma_f32_16x16x32_bf16(a[i], bb[j],
                                                              acc[i][j], 0, 0, 0);
    }
  }

  const float ls = fmaxf(logit_scale[0], 0.01f);
  // diag possible iff this block's row-range overlaps its col-range
  const bool diag_block = ((n0 >> 8) == (m0 >> 8));
#pragma unroll
  for (int i = 0; i < 4; ++i)
#pragma unroll
    for (int j = 0; j < 8; ++j)
#pragma unroll
      for (int r = 0; r < 4; ++r) {
        const int nr = n0 + wm * 64 + i * 16 + quad * 4 + r;  // S row
        const int mc = m0 + wn * 128 + j * 16 + lr;           // S col
        float v = acc[i][j][r] * HD_SCALE;
        if (diag_block && nr == mc) v += dvec[b * 1024 + nr];
        __builtin_nontemporal_store(v * ls,
            &out[((size_t)b << 20) + (size_t)nr * 1024 + mc]);
      }
}

// ---------------------------------------------------------------------------
extern "C" void kernel_launch(void* const* d_in, const int* in_sizes, int n_in,
                              void* d_out, int out_size, void* d_ws, size_t ws_size,
                              hipStream_t stream) {
  const float* feats = (const float*)d_in[0];  // (16, 2049, 256)
  const float* Wq = (const float*)d_in[1];     // (192, 256)
  const float* Wk = (const float*)d_in[2];     // (192, 256)
  const float* Wd = (const float*)d_in[3];     // (1, 256)
  const float* bd = (const float*)d_in[4];     // (1,)
  const float* ls = (const float*)d_in[5];     // scalar
  float* out = (float*)d_out;                  // (16, 1024, 1024) fp32

  uint8_t* ws = (uint8_t*)d_ws;
  unsigned short* xb = (unsigned short*)ws;                          // 8 MB bf16 x
  unsigned short* QK = (unsigned short*)(ws + (8u << 20));           // 12 MB bf16 [Q|K]
  float* dvec = (float*)(ws + (20u << 20));                          // 64 KB fp32 d
  unsigned short* Wqkb = (unsigned short*)(ws + (20u << 20) + (64u << 10));  // 192 KB

  hipLaunchKernelGGL(k_prep, dim3(4096), dim3(256), 0, stream, feats, Wq, Wk, Wd, bd,
                     xb, dvec, Wqkb);
  hipLaunchKernelGGL(k_proj, dim3(128, 6), dim3(256), 0, stream, xb, Wqkb, QK);
  hipLaunchKernelGGL(k_score, dim3(4, 8, 16), dim3(256), 0, stream, QK, dvec, ls, out);
}

// Round 6
// 123.959 us; speedup vs baseline: 1.1961x; 1.0673x over previous
//
#include <hip/hip_runtime.h>
#include <stdint.h>

// ScoreNet: S[b] = (x_b Wq^T)(x_b Wk^T)^T * (1/sqrt(R)) + diag(x_b Wd^T + bd), * max(ls, 0.01)
// B=16, L=2048 -> N=1024, C=256, H*R=192.
//
// R6: k_prep unchanged; k_proj = 128x64 tiles (768 blocks, 3/CU balanced);
// k_score = R2's 128x128/BK=64 swizzled structure + XCD-aware batch remap
// (each XCD owns 2 batches -> Q/K staging hits local L2 after first touch).

#define HD_SCALE 0.17677669529663687f  // 1/sqrt(32)

typedef __bf16 bf16_t;
typedef bf16_t bf16x8 __attribute__((ext_vector_type(8)));
typedef float f32x4 __attribute__((ext_vector_type(4)));

__device__ __forceinline__ unsigned short f2bf(float f) {
  unsigned int u = __float_as_uint(f);
  return (unsigned short)((u + 0x7fffu + ((u >> 16) & 1u)) >> 16);
}

__device__ __forceinline__ void gload16(const void* g, void* l) {
  __builtin_amdgcn_global_load_lds(
      (const __attribute__((address_space(1))) void*)g,
      (__attribute__((address_space(3))) void*)l, 16, 0, 0);
}

// ---------------------------------------------------------------------------
// Kernel 1: fold pairs of rows (mean) -> xb (bf16), d = x.Wd + bd (fp32),
// and (first 384 blocks) pack [Wq;Wk] fp32 -> bf16.
// ---------------------------------------------------------------------------
__global__ __launch_bounds__(256) void k_prep(const float* __restrict__ feats,
                                              const float* __restrict__ Wq,
                                              const float* __restrict__ Wk,
                                              const float* __restrict__ Wd,
                                              const float* __restrict__ bd,
                                              unsigned short* __restrict__ xb,
                                              float* __restrict__ dvec,
                                              unsigned short* __restrict__ Wqkb) {
  const int t = threadIdx.x;
  if (blockIdx.x < 384) {
    const int idx = blockIdx.x * 256 + t;
    const float v = (idx < 49152) ? Wq[idx] : Wk[idx - 49152];
    Wqkb[idx] = f2bf(v);
  }
  const int wave = t >> 6, lane = t & 63;
  const int gr = blockIdx.x * 4 + wave;
  const int b = gr >> 10, n = gr & 1023;
  const int c = lane * 4;

  const float* r0 = feats + (size_t)(b * 2049 + 1 + 2 * n) * 256 + c;
  float4 p0 = *(const float4*)r0;
  float4 p1 = *(const float4*)(r0 + 256);
  float4 wv = *(const float4*)(Wd + c);

  float x0 = (p0.x + p1.x) * 0.5f;
  float x1 = (p0.y + p1.y) * 0.5f;
  float x2 = (p0.z + p1.z) * 0.5f;
  float x3 = (p0.w + p1.w) * 0.5f;

  ushort4 xs;
  xs.x = f2bf(x0); xs.y = f2bf(x1); xs.z = f2bf(x2); xs.w = f2bf(x3);
  *(ushort4*)&xb[(size_t)gr * 256 + c] = xs;

  float dot = x0 * wv.x + x1 * wv.y + x2 * wv.z + x3 * wv.w;
#pragma unroll
  for (int o = 32; o > 0; o >>= 1) dot += __shfl_down(dot, o, 64);
  if (lane == 0) dvec[gr] = dot + bd[0];
}

// ---------------------------------------------------------------------------
// Kernel 2: QK[16384][384] = xb[16384][256] @ Wqkb[384][256]^T
// 128x64 tile, BK=64, XOR-swizzled LDS, grid (128,6)=768 blocks (3/CU).
// A-tile sharers sit at flat-stride 128 (== 0 mod 8) -> same XCD already.
// ---------------------------------------------------------------------------
__global__ __launch_bounds__(256) void k_proj(const unsigned short* __restrict__ xb,
                                              const unsigned short* __restrict__ Wqkb,
                                              unsigned short* __restrict__ QK) {
  __shared__ unsigned short As[128 * 64];  // 16 KB
  __shared__ unsigned short Bs[64 * 64];   // 8 KB
  const int t = threadIdx.x;
  const int w = t >> 6, l = t & 63;
  const int m0 = blockIdx.x * 128;  // rows in 16384
  const int n0 = blockIdx.y * 64;   // cols in 384
  const int wm = w >> 1, wn = w & 1;
  const int quad = l >> 4, lr = l & 15;

  f32x4 acc[4][2] = {};

  for (int kk = 0; kk < 4; ++kk) {
    const int k0 = kk * 64;
    __syncthreads();
#pragma unroll
    for (int i = 0; i < 4; ++i) {  // A: 1024 chunks
      const int e = i * 256 + t;
      const int row = e >> 3;
      const int kc = (e & 7) ^ (row & 7);
      gload16(xb + (size_t)(m0 + row) * 256 + k0 + kc * 8,
              &As[(i * 256 + (w << 6)) * 8]);
    }
#pragma unroll
    for (int i = 0; i < 2; ++i) {  // B: 512 chunks
      const int e = i * 256 + t;
      const int row = e >> 3;
      const int kc = (e & 7) ^ (row & 7);
      gload16(Wqkb + (size_t)(n0 + row) * 256 + k0 + kc * 8,
              &Bs[(i * 256 + (w << 6)) * 8]);
    }
    __syncthreads();

#pragma unroll
    for (int s = 0; s < 2; ++s) {
      bf16x8 a[4], bb[2];
#pragma unroll
      for (int i = 0; i < 4; ++i) {
        const int row = wm * 64 + i * 16 + lr;
        const int pos = (s * 4 + quad) ^ (row & 7);
        a[i] = *(const bf16x8*)&As[row * 64 + pos * 8];
      }
#pragma unroll
      for (int j = 0; j < 2; ++j) {
        const int row = wn * 32 + j * 16 + lr;
        const int pos = (s * 4 + quad) ^ (row & 7);
        bb[j] = *(const bf16x8*)&Bs[row * 64 + pos * 8];
      }
#pragma unroll
      for (int i = 0; i < 4; ++i)
#pragma unroll
        for (int j = 0; j < 2; ++j)
          acc[i][j] = __builtin_amdgcn_mfma_f32_16x16x32_bf16(a[i], bb[j],
                                                              acc[i][j], 0, 0, 0);
    }
  }

#pragma unroll
  for (int i = 0; i < 4; ++i)
#pragma unroll
    for (int j = 0; j < 2; ++j)
#pragma unroll
      for (int r = 0; r < 4; ++r) {
        const int row = m0 + wm * 64 + i * 16 + quad * 4 + r;
        const int col = n0 + wn * 32 + j * 16 + lr;
        QK[(size_t)row * 384 + col] = f2bf(acc[i][j][r]);
      }
}

// ---------------------------------------------------------------------------
// Kernel 3: S[b] = Q[b] @ K[b]^T * HD_SCALE (+ diag d) * ls
// 128x128 tile, BK=64 (3 iters), XOR-swizzled LDS (R2 structure).
// XCD-aware remap: flat&7 selects XCD under round-robin dispatch; XCD x
// owns batches {2x, 2x+1} -> its 1.5 MB Q/K working set lives in local L2.
// ---------------------------------------------------------------------------
__global__ __launch_bounds__(256) void k_score(const unsigned short* __restrict__ QK,
                                               const float* __restrict__ dvec,
                                               const float* __restrict__ logit_scale,
                                               float* __restrict__ out) {
  __shared__ unsigned short As[128 * 64];  // 16 KB
  __shared__ unsigned short Bs[128 * 64];  // 16 KB
  const int t = threadIdx.x;
  const int w = t >> 6, l = t & 63;

  // flat 0..1023 over grid (8,8,16), x-fastest dispatch order
  const int flat = blockIdx.x + (blockIdx.y << 3) + (blockIdx.z << 6);
  const int xcd = flat & 7, j0 = flat >> 3;            // j0 in [0,128)
  const int b = (xcd << 1) | (j0 >> 6);                // batch 0..15
  const int jj = j0 & 63;
  const int mt = jj & 7, nt = jj >> 3;

  const int m0 = mt * 128;  // cols of S (K rows)
  const int n0 = nt * 128;  // rows of S (Q rows)
  const int wm = w >> 1, wn = w & 1;
  const int quad = l >> 4, lr = l & 15;
  const size_t qbase = (size_t)b * 1024 * 384;

  f32x4 acc[4][4] = {};

  for (int kk = 0; kk < 3; ++kk) {
    const int k0 = kk * 64;
    __syncthreads();
#pragma unroll
    for (int i = 0; i < 4; ++i) {
      const int e = i * 256 + t;
      const int row = e >> 3;
      const int kc = (e & 7) ^ (row & 7);
      gload16(QK + qbase + (size_t)(n0 + row) * 384 + k0 + kc * 8,
              &As[(i * 256 + (w << 6)) * 8]);
      gload16(QK + qbase + (size_t)(m0 + row) * 384 + 192 + k0 + kc * 8,
              &Bs[(i * 256 + (w << 6)) * 8]);
    }
    __syncthreads();

#pragma unroll
    for (int s = 0; s < 2; ++s) {
      bf16x8 a[4], bb[4];
#pragma unroll
      for (int i = 0; i < 4; ++i) {
        const int row = wm * 64 + i * 16 + lr;
        const int pos = (s * 4 + quad) ^ (row & 7);
        a[i] = *(const bf16x8*)&As[row * 64 + pos * 8];
      }
#pragma unroll
      for (int j = 0; j < 4; ++j) {
        const int row = wn * 64 + j * 16 + lr;
        const int pos = (s * 4 + quad) ^ (row & 7);
        bb[j] = *(const bf16x8*)&Bs[row * 64 + pos * 8];
      }
#pragma unroll
      for (int i = 0; i < 4; ++i)
#pragma unroll
        for (int j = 0; j < 4; ++j)
          acc[i][j] = __builtin_amdgcn_mfma_f32_16x16x32_bf16(a[i], bb[j],
                                                              acc[i][j], 0, 0, 0);
    }
  }

  const float ls = fmaxf(logit_scale[0], 0.01f);
  const bool diag_block = (m0 == n0);
#pragma unroll
  for (int i = 0; i < 4; ++i)
#pragma unroll
    for (int j = 0; j < 4; ++j)
#pragma unroll
      for (int r = 0; r < 4; ++r) {
        const int nr = n0 + wm * 64 + i * 16 + quad * 4 + r;  // S row
        const int mc = m0 + wn * 64 + j * 16 + lr;            // S col
        float v = acc[i][j][r] * HD_SCALE;
        if (diag_block && nr == mc) v += dvec[b * 1024 + nr];
        __builtin_nontemporal_store(v * ls,
            &out[((size_t)b << 20) + (size_t)nr * 1024 + mc]);
      }
}

// ---------------------------------------------------------------------------
extern "C" void kernel_launch(void* const* d_in, const int* in_sizes, int n_in,
                              void* d_out, int out_size, void* d_ws, size_t ws_size,
                              hipStream_t stream) {
  const float* feats = (const float*)d_in[0];  // (16, 2049, 256)
  const float* Wq = (const float*)d_in[1];     // (192, 256)
  const float* Wk = (const float*)d_in[2];     // (192, 256)
  const float* Wd = (const float*)d_in[3];     // (1, 256)
  const float* bd = (const float*)d_in[4];     // (1,)
  const float* ls = (const float*)d_in[5];     // scalar
  float* out = (float*)d_out;                  // (16, 1024, 1024) fp32

  uint8_t* ws = (uint8_t*)d_ws;
  unsigned short* xb = (unsigned short*)ws;                          // 8 MB bf16 x
  unsigned short* QK = (unsigned short*)(ws + (8u << 20));           // 12 MB bf16 [Q|K]
  float* dvec = (float*)(ws + (20u << 20));                          // 64 KB fp32 d
  unsigned short* Wqkb = (unsigned short*)(ws + (20u << 20) + (64u << 10));  // 192 KB

  hipLaunchKernelGGL(k_prep, dim3(4096), dim3(256), 0, stream, feats, Wq, Wk, Wd, bd,
                     xb, dvec, Wqkb);
  hipLaunchKernelGGL(k_proj, dim3(128, 6), dim3(256), 0, stream, xb, Wqkb, QK);
  hipLaunchKernelGGL(k_score, dim3(8, 8, 16), dim3(256), 0, stream, QK, dvec, ls, out);
}